// Round 9
// baseline (426.667 us; speedup 1.0000x reference)
//
#include <hip/hip_runtime.h>
#include <hip/hip_cooperative_groups.h>

namespace cg = cooperative_groups;

#define SEQ 4096
#define DM 1024
#define NH 16
#define DK 64

typedef _Float16 half8 __attribute__((ext_vector_type(8)));
typedef _Float16 half4v __attribute__((ext_vector_type(4)));
typedef float f32x4 __attribute__((ext_vector_type(4)));

#define MFMA16(a, b, c) __builtin_amdgcn_mfma_f32_16x16x32_f16((a), (b), (c), 0, 0, 0)
#define GLOAD_LDS(g, l)                                                                  \
    __builtin_amdgcn_global_load_lds((const __attribute__((address_space(1))) void*)(g), \
                                     (__attribute__((address_space(3))) void*)(l), 16, 0, 0)

// ---------------- m97-structure f16 GEMM, BK=64 (R6 body, best measured) ----------------
template <int MT>  // M-tile: 128 (qkv) or 64 (out); N-tile fixed 128
__device__ __forceinline__ void gemm_bk64(const _Float16* __restrict__ A,
                                          const _Float16* __restrict__ B, int m0, int n0,
                                          _Float16* As, _Float16* Bs, f32x4 (*acc)[4]) {
    constexpr int MI = MT / 32;
    constexpr int ACH = MT / 64;
    const int tid = threadIdx.x;
    const int wave = tid >> 6, lane = tid & 63;
    const int quad = lane >> 4, l16 = lane & 15;
    const int wr = (wave >> 1) * (MT / 2);
    const int wc = (wave & 1) * 64;
    const int srow = tid >> 2, scol = (tid & 3) * 8;

    for (int k0 = 0; k0 < DM; k0 += 64) {
#pragma unroll
        for (int p = 0; p < 2; ++p) {
            int kc = k0 + p * 32 + scol;
#pragma unroll
            for (int j = 0; j < ACH; ++j)
                GLOAD_LDS(A + (size_t)(m0 + j * 64 + srow) * DM + kc,
                          As + p * (MT * 32) + j * 2048 + tid * 8);
#pragma unroll
            for (int j = 0; j < 2; ++j)
                GLOAD_LDS(B + (size_t)(n0 + j * 64 + srow) * DM + kc,
                          Bs + p * 4096 + j * 2048 + tid * 8);
        }
        __syncthreads();
#pragma unroll
        for (int p = 0; p < 2; ++p) {
            half8 af[MI], bf[4];
#pragma unroll
            for (int mi = 0; mi < MI; ++mi)
                af[mi] = *(const half8*)&As[p * (MT * 32) + (wr + mi * 16 + l16) * 32 + quad * 8];
#pragma unroll
            for (int ni = 0; ni < 4; ++ni)
                bf[ni] = *(const half8*)&Bs[p * 4096 + (wc + ni * 16 + l16) * 32 + quad * 8];
#pragma unroll
            for (int mi = 0; mi < MI; ++mi)
#pragma unroll
                for (int ni = 0; ni < 4; ++ni)
                    acc[mi][ni] = MFMA16(af[mi], bf[ni], acc[mi][ni]);
        }
        __syncthreads();
    }
}

// ---------------- single cooperative kernel: cvt -> qkv -> attn -> out ----------------
// grid = 512 = EXACTLY 2 blocks/CU, guaranteed co-resident: launch_bounds(256,2) gives a
// 256-VGPR budget (worst phase ~150) and 2x32KB=64KB LDS/CU (<160). R8's (256,3)/768
// failed: fused register demand exceeded the 170-reg cap -> occupancy 2 -> cooperative
// launch rejected -> silent zero output (absmax 0.64 == max|ref|).
__global__ void __launch_bounds__(256, 2) fused_mha(
    const float* __restrict__ q, const float* __restrict__ k, const float* __restrict__ v,
    const float* __restrict__ wq, const float* __restrict__ bq, const float* __restrict__ wk,
    const float* __restrict__ bk, const float* __restrict__ wv, const float* __restrict__ bv,
    const float* __restrict__ wo, const float* __restrict__ bo, char* __restrict__ ws,
    float* __restrict__ out) {
    __shared__ _Float16 As[2 * 128 * 32];  // 16 KB; P2 aliases Pl on top
    __shared__ _Float16 Bs[2 * 128 * 32];  // 16 KB

    const size_t SZ_T = (size_t)SEQ * DM * sizeof(_Float16);  // 8 MB
    const size_t SZ_W = (size_t)DM * DM * sizeof(_Float16);   // 2 MB
    _Float16* qh  = (_Float16*)(ws);
    _Float16* kh  = (_Float16*)(ws + SZ_T);
    _Float16* vh  = (_Float16*)(ws + 2 * SZ_T);
    _Float16* wqh = (_Float16*)(ws + 3 * SZ_T);
    _Float16* wkh = (_Float16*)(ws + 3 * SZ_T + SZ_W);
    _Float16* wvh = (_Float16*)(ws + 3 * SZ_T + 2 * SZ_W);
    _Float16* woh = (_Float16*)(ws + 3 * SZ_T + 3 * SZ_W);
    _Float16* Qo  = (_Float16*)(ws + 3 * SZ_T + 4 * SZ_W);
    _Float16* Ko  = (_Float16*)(ws + 4 * SZ_T + 4 * SZ_W);
    _Float16* Vt  = (_Float16*)(ws + 5 * SZ_T + 4 * SZ_W);
    _Float16* Xh  = qh;  // qh dead after P1

    cg::grid_group grid = cg::this_grid();
    const int tid = threadIdx.x;
    const int wave = tid >> 6, lane = tid & 63;
    const int quad = lane >> 4, l16 = lane & 15;

    // ---------------- P0: fp32 -> fp16 conversion (grid-strided, 16B stores) ----------
    {
        const int gbase = (blockIdx.x * 256 + tid) * 8;
        const int stride = 512 * 256 * 8;  // 1,048,576 elems/sweep
#pragma unroll 1
        for (int z = 0; z < 7; ++z) {
            const float* src;
            _Float16* dst;
            int n;
            switch (z) {
            case 0: src = q;  dst = qh;  n = SEQ * DM; break;
            case 1: src = k;  dst = kh;  n = SEQ * DM; break;
            case 2: src = v;  dst = vh;  n = SEQ * DM; break;
            case 3: src = wq; dst = wqh; n = DM * DM;  break;
            case 4: src = wk; dst = wkh; n = DM * DM;  break;
            case 5: src = wv; dst = wvh; n = DM * DM;  break;
            default: src = wo; dst = woh; n = DM * DM; break;
            }
#pragma unroll 1
            for (int i = gbase; i < n; i += stride) {
                float4 f0 = *(const float4*)(src + i);
                float4 f1 = *(const float4*)(src + i + 4);
                half8 h;
                h[0] = (_Float16)f0.x; h[1] = (_Float16)f0.y;
                h[2] = (_Float16)f0.z; h[3] = (_Float16)f0.w;
                h[4] = (_Float16)f1.x; h[5] = (_Float16)f1.y;
                h[6] = (_Float16)f1.z; h[7] = (_Float16)f1.w;
                *(half8*)(dst + i) = h;
            }
        }
    }
    grid.sync();

    // ------------- P1: QKV projections, 768 128x128 tiles over 512 blocks -------------
    {
#pragma unroll 1
        for (int t = blockIdx.x; t < 768; t += 512) {
            const int z = t >> 8;    // 0:Q 1:K 2:V
            const int tt = t & 255;  // 32 m-tiles x 8 n-tiles
            const int m0 = (tt >> 3) * 128;
            const int n0 = (tt & 7) * 128;
            const _Float16* A = (z == 0) ? qh : (z == 1) ? kh : vh;
            const _Float16* B = (z == 0) ? wqh : (z == 1) ? wkh : wvh;
            const float* bias = (z == 0) ? bq : (z == 1) ? bk : bv;
            const float scale = (z == 0) ? 0.125f : 1.0f;  // 1/sqrt(64) folded into Q

            f32x4 acc[4][4] = {};
            gemm_bk64<128>(A, B, m0, n0, As, Bs, acc);

            const int wr = (wave >> 1) * 64;
            const int wc = (wave & 1) * 64;
            float bs[4];
#pragma unroll
            for (int ni = 0; ni < 4; ++ni) bs[ni] = bias[n0 + wc + ni * 16 + l16];

            if (z < 2) {
                _Float16* C = (z == 0) ? Qo : Ko;
#pragma unroll
                for (int mi = 0; mi < 4; ++mi)
#pragma unroll
                    for (int ni = 0; ni < 4; ++ni) {
                        int m = m0 + wr + mi * 16 + quad * 4;
                        int n = n0 + wc + ni * 16 + l16;
#pragma unroll
                        for (int r = 0; r < 4; ++r)
                            C[(size_t)(m + r) * DM + n] =
                                (_Float16)((acc[mi][ni][r] + bs[ni]) * scale);
                    }
            } else {
#pragma unroll
                for (int mi = 0; mi < 4; ++mi)
#pragma unroll
                    for (int ni = 0; ni < 4; ++ni) {
                        int m = m0 + wr + mi * 16 + quad * 4;
                        int n = n0 + wc + ni * 16 + l16;
                        half4v p;
#pragma unroll
                        for (int r = 0; r < 4; ++r) p[r] = (_Float16)(acc[mi][ni][r] + bs[ni]);
                        *(half4v*)(Vt + (size_t)n * SEQ + m) = p;  // m%4==0 -> 8B aligned
                    }
            }
        }
    }
    grid.sync();

    // ---------------- P2: windowed attention (R6 body), 4096 units / 2048 waves -------
    {
        _Float16(*Pl)[16][32] = (_Float16(*)[16][32])As;  // 4 KB alias, per-wave slices
        const int gw = blockIdx.x * 4 + wave;             // 0..2047
#pragma unroll 1
        for (int u = gw; u < 4096; u += 2048) {
            const int h = u & 15;
            const int q0 = (u >> 4) * 16;

            const _Float16* Qp = Qo + (size_t)(q0 + l16) * DM + h * DK + quad * 8;
            half8 aq0 = *(const half8*)(Qp);
            half8 aq1 = *(const half8*)(Qp + 32);

            float rowM[4], rowL[4];
            f32x4 o[4] = {};
#pragma unroll
            for (int r = 0; r < 4; ++r) { rowM[r] = -__builtin_inff(); rowL[r] = 0.f; }

            int kstart = (q0 > 127) ? ((q0 - 127) & ~31) : 0;
            int kend = q0 + 143;
            if (kend > SEQ - 1) kend = SEQ - 1;

            for (int kt = kstart; kt <= kend; kt += 32) {
                f32x4 s[2];
#pragma unroll
                for (int cf = 0; cf < 2; ++cf) {
                    int krow = kt + cf * 16 + l16;
                    const _Float16* Kp = Ko + (size_t)krow * DM + h * DK + quad * 8;
                    half8 b0 = *(const half8*)(Kp);
                    half8 b1 = *(const half8*)(Kp + 32);
                    f32x4 zz = {};
                    zz = MFMA16(aq0, b0, zz);
                    zz = MFMA16(aq1, b1, zz);
                    s[cf] = zz;
                }
                float mnew[4], alpha[4];
#pragma unroll
                for (int r = 0; r < 4; ++r) {
                    int row = q0 + quad * 4 + r;
#pragma unroll
                    for (int cf = 0; cf < 2; ++cf) {
                        int key = kt + cf * 16 + l16;
                        bool valid = (key >= row - 127) && (key <= row + 128);
                        if (!valid) s[cf][r] = -1e30f;
                    }
                    float t = fmaxf(s[0][r], s[1][r]);
#pragma unroll
                    for (int off = 1; off < 16; off <<= 1) t = fmaxf(t, __shfl_xor(t, off));
                    mnew[r] = fmaxf(rowM[r], t);
                    alpha[r] = __expf(rowM[r] - mnew[r]);
                    float p0 = __expf(s[0][r] - mnew[r]);
                    float p1 = __expf(s[1][r] - mnew[r]);
                    Pl[wave][quad * 4 + r][l16] = (_Float16)p0;
                    Pl[wave][quad * 4 + r][l16 + 16] = (_Float16)p1;
                    float rs = p0 + p1;
#pragma unroll
                    for (int off = 1; off < 16; off <<= 1) rs += __shfl_xor(rs, off);
                    rowL[r] = rowL[r] * alpha[r] + rs;
                    rowM[r] = mnew[r];
                }
#pragma unroll
                for (int ni = 0; ni < 4; ++ni)
#pragma unroll
                    for (int r = 0; r < 4; ++r) o[ni][r] *= alpha[r];
                half8 ap = *(const half8*)&Pl[wave][l16][quad * 8];
#pragma unroll
                for (int ni = 0; ni < 4; ++ni) {
                    const _Float16* Vp =
                        Vt + (size_t)(h * DK + ni * 16 + l16) * SEQ + kt + quad * 8;
                    half8 bv = *(const half8*)(Vp);
                    o[ni] = MFMA16(ap, bv, o[ni]);
                }
            }

            float rinv[4];
#pragma unroll
            for (int r = 0; r < 4; ++r) rinv[r] = 1.0f / rowL[r];
#pragma unroll
            for (int ni = 0; ni < 4; ++ni) {
                int n = h * DK + ni * 16 + l16;
#pragma unroll
                for (int r = 0; r < 4; ++r) {
                    int m = q0 + quad * 4 + r;
                    Xh[(size_t)m * DM + n] = (_Float16)(o[ni][r] * rinv[r]);
                }
            }
        }
    }
    grid.sync();

    // ------------- P3: output projection, 512 64x128 tiles, blocks 1:1 ----------------
    {
        const int m0 = (blockIdx.x >> 3) * 64;
        const int n0 = (blockIdx.x & 7) * 128;
        f32x4 acc[2][4] = {};
        gemm_bk64<64>(Xh, woh, m0, n0, As, Bs, acc);

        const int wr = (wave >> 1) * 32;
        const int wc = (wave & 1) * 64;
#pragma unroll
        for (int mi = 0; mi < 2; ++mi)
#pragma unroll
            for (int ni = 0; ni < 4; ++ni) {
                int m = m0 + wr + mi * 16 + quad * 4;
                int n = n0 + wc + ni * 16 + l16;
                float b = bo[n];
#pragma unroll
                for (int r = 0; r < 4; ++r) out[(size_t)(m + r) * DM + n] = acc[mi][ni][r] + b;
            }
    }
}

extern "C" void kernel_launch(void* const* d_in, const int* in_sizes, int n_in, void* d_out,
                              int out_size, void* d_ws, size_t ws_size, hipStream_t stream) {
    const float* q  = (const float*)d_in[0];
    const float* k  = (const float*)d_in[1];
    const float* v  = (const float*)d_in[2];
    const float* wq = (const float*)d_in[3];
    const float* bq = (const float*)d_in[4];
    const float* wk = (const float*)d_in[5];
    const float* bk = (const float*)d_in[6];
    const float* wv = (const float*)d_in[7];
    const float* bv = (const float*)d_in[8];
    const float* wo = (const float*)d_in[9];
    const float* bo = (const float*)d_in[10];
    char* ws = (char*)d_ws;
    float* out = (float*)d_out;

    void* args[] = {&q, &k, &v, &wq, &bq, &wk, &bk, &wv, &bv, &wo, &bo, &ws, &out};
    hipLaunchCooperativeKernel((const void*)fused_mha, dim3(512), dim3(256), args, 0, stream);
}

// Round 10
// 207.819 us; speedup vs baseline: 2.0531x; 2.0531x over previous
//
#include <hip/hip_runtime.h>

#define SEQ 4096
#define DM 1024
#define NH 16
#define DK 64

typedef _Float16 half8 __attribute__((ext_vector_type(8)));
typedef _Float16 half4v __attribute__((ext_vector_type(4)));
typedef float f32x4 __attribute__((ext_vector_type(4)));

#define MFMA16(a, b, c) __builtin_amdgcn_mfma_f32_16x16x32_f16((a), (b), (c), 0, 0, 0)
#define GLOAD_LDS(g, l)                                                                  \
    __builtin_amdgcn_global_load_lds((const __attribute__((address_space(1))) void*)(g), \
                                     (__attribute__((address_space(3))) void*)(l), 16, 0, 0)

// all-16-lane max via DPP (VALU pipe, ~5cyc/step) -- replaces 4-deep ds_bpermute chain
__device__ __forceinline__ float dpp_max16(float x) {
    x = fmaxf(x, __int_as_float(__builtin_amdgcn_update_dpp(
                     0, __float_as_int(x), 0xB1, 0xF, 0xF, true)));  // quad_perm xor1
    x = fmaxf(x, __int_as_float(__builtin_amdgcn_update_dpp(
                     0, __float_as_int(x), 0x4E, 0xF, 0xF, true)));  // quad_perm xor2
    x = fmaxf(x, __int_as_float(__builtin_amdgcn_update_dpp(
                     0, __float_as_int(x), 0x124, 0xF, 0xF, true)));  // row_ror:4
    x = fmaxf(x, __int_as_float(__builtin_amdgcn_update_dpp(
                     0, __float_as_int(x), 0x128, 0xF, 0xF, true)));  // row_ror:8
    return x;
}

// ---------------- fp32 -> fp16 conversion (7 tensors in one launch, 16B stores) --------
__global__ void cvt_all(const float* __restrict__ q, const float* __restrict__ k,
                        const float* __restrict__ v, const float* __restrict__ wq,
                        const float* __restrict__ wk, const float* __restrict__ wv,
                        const float* __restrict__ wo, _Float16* __restrict__ qh,
                        _Float16* __restrict__ kh, _Float16* __restrict__ vh,
                        _Float16* __restrict__ wqh, _Float16* __restrict__ wkh,
                        _Float16* __restrict__ wvh, _Float16* __restrict__ woh) {
    int z = blockIdx.y;
    const float* src;
    _Float16* dst;
    int n;
    switch (z) {
    case 0: src = q;  dst = qh;  n = SEQ * DM; break;
    case 1: src = k;  dst = kh;  n = SEQ * DM; break;
    case 2: src = v;  dst = vh;  n = SEQ * DM; break;
    case 3: src = wq; dst = wqh; n = DM * DM;  break;
    case 4: src = wk; dst = wkh; n = DM * DM;  break;
    case 5: src = wv; dst = wvh; n = DM * DM;  break;
    default: src = wo; dst = woh; n = DM * DM; break;
    }
    int idx = (blockIdx.x * 256 + threadIdx.x) * 8;
    if (idx >= n) return;
    float4 f0 = *(const float4*)(src + idx);
    float4 f1 = *(const float4*)(src + idx + 4);
    half8 h;
    h[0] = (_Float16)f0.x; h[1] = (_Float16)f0.y; h[2] = (_Float16)f0.z; h[3] = (_Float16)f0.w;
    h[4] = (_Float16)f1.x; h[5] = (_Float16)f1.y; h[6] = (_Float16)f1.z; h[7] = (_Float16)f1.w;
    *(half8*)(dst + idx) = h;
}

// ---------------- m97-structure f16 GEMM, BK=64 (R6 body, best measured) ----------------
template <int MT>  // M-tile: 128 (qkv) or 64 (out); N-tile fixed 128
__device__ __forceinline__ void gemm_bk64(const _Float16* __restrict__ A,
                                          const _Float16* __restrict__ B, int m0, int n0,
                                          _Float16* As, _Float16* Bs, f32x4 (*acc)[4]) {
    constexpr int MI = MT / 32;
    constexpr int ACH = MT / 64;
    const int tid = threadIdx.x;
    const int wave = tid >> 6, lane = tid & 63;
    const int quad = lane >> 4, l16 = lane & 15;
    const int wr = (wave >> 1) * (MT / 2);
    const int wc = (wave & 1) * 64;
    const int srow = tid >> 2, scol = (tid & 3) * 8;

    for (int k0 = 0; k0 < DM; k0 += 64) {
#pragma unroll
        for (int p = 0; p < 2; ++p) {
            int kc = k0 + p * 32 + scol;
#pragma unroll
            for (int j = 0; j < ACH; ++j)
                GLOAD_LDS(A + (size_t)(m0 + j * 64 + srow) * DM + kc,
                          As + p * (MT * 32) + j * 2048 + tid * 8);
#pragma unroll
            for (int j = 0; j < 2; ++j)
                GLOAD_LDS(B + (size_t)(n0 + j * 64 + srow) * DM + kc,
                          Bs + p * 4096 + j * 2048 + tid * 8);
        }
        __syncthreads();
#pragma unroll
        for (int p = 0; p < 2; ++p) {
            half8 af[MI], bf[4];
#pragma unroll
            for (int mi = 0; mi < MI; ++mi)
                af[mi] = *(const half8*)&As[p * (MT * 32) + (wr + mi * 16 + l16) * 32 + quad * 8];
#pragma unroll
            for (int ni = 0; ni < 4; ++ni)
                bf[ni] = *(const half8*)&Bs[p * 4096 + (wc + ni * 16 + l16) * 32 + quad * 8];
#pragma unroll
            for (int mi = 0; mi < MI; ++mi)
#pragma unroll
                for (int ni = 0; ni < 4; ++ni)
                    acc[mi][ni] = MFMA16(af[mi], bf[ni], acc[mi][ni]);
        }
        __syncthreads();
    }
}

// ---------------- QKV projections: 128x128 tiles, grid (32,8,3) = 3 blocks/CU ----------
__global__ void __launch_bounds__(256, 3) gemm_qkv(
    const _Float16* __restrict__ qh, const _Float16* __restrict__ kh,
    const _Float16* __restrict__ vh, const _Float16* __restrict__ wqh,
    const _Float16* __restrict__ wkh, const _Float16* __restrict__ wvh,
    const float* __restrict__ bq, const float* __restrict__ bk, const float* __restrict__ bv,
    _Float16* __restrict__ Qo, _Float16* __restrict__ Ko, _Float16* __restrict__ Vt) {
    __shared__ _Float16 As[2 * 128 * 32];
    __shared__ _Float16 Bs[2 * 128 * 32];
    int z = blockIdx.z;
    const _Float16 *A, *B;
    const float* bias;
    float scale;
    if (z == 0) { A = qh; B = wqh; bias = bq; scale = 0.125f; }  // 1/sqrt(64)
    else if (z == 1) { A = kh; B = wkh; bias = bk; scale = 1.0f; }
    else { A = vh; B = wvh; bias = bv; scale = 1.0f; }

    int m0 = blockIdx.x * 128;
    int n0 = blockIdx.y * 128;
    f32x4 acc[4][4] = {};
    gemm_bk64<128>(A, B, m0, n0, As, Bs, acc);

    const int tid = threadIdx.x;
    const int wave = tid >> 6, lane = tid & 63;
    const int quad = lane >> 4, l16 = lane & 15;
    const int wr = (wave >> 1) * 64;
    const int wc = (wave & 1) * 64;
    float bs[4];
#pragma unroll
    for (int ni = 0; ni < 4; ++ni) bs[ni] = bias[n0 + wc + ni * 16 + l16];

    if (z < 2) {
        _Float16* C = (z == 0) ? Qo : Ko;
#pragma unroll
        for (int mi = 0; mi < 4; ++mi)
#pragma unroll
            for (int ni = 0; ni < 4; ++ni) {
                int m = m0 + wr + mi * 16 + quad * 4;
                int n = n0 + wc + ni * 16 + l16;
#pragma unroll
                for (int r = 0; r < 4; ++r)
                    C[(size_t)(m + r) * DM + n] = (_Float16)((acc[mi][ni][r] + bs[ni]) * scale);
            }
    } else {
#pragma unroll
        for (int mi = 0; mi < 4; ++mi)
#pragma unroll
            for (int ni = 0; ni < 4; ++ni) {
                int m = m0 + wr + mi * 16 + quad * 4;
                int n = n0 + wc + ni * 16 + l16;
                half4v p;
#pragma unroll
                for (int r = 0; r < 4; ++r) p[r] = (_Float16)(acc[mi][ni][r] + bs[ni]);
                *(half4v*)(Vt + (size_t)n * SEQ + m) = p;  // m % 4 == 0 -> 8B aligned
            }
    }
}

// ---------------- output projection: 64x128 tiles, grid (64,8) = 2 blocks/CU ----------
__global__ void __launch_bounds__(256, 3) gemm_out(const _Float16* __restrict__ Xh,
                                                   const _Float16* __restrict__ woh,
                                                   const float* __restrict__ bo,
                                                   float* __restrict__ out) {
    __shared__ _Float16 As[2 * 64 * 32];
    __shared__ _Float16 Bs[2 * 128 * 32];
    int m0 = blockIdx.x * 64;
    int n0 = blockIdx.y * 128;
    f32x4 acc[2][4] = {};
    gemm_bk64<64>(Xh, woh, m0, n0, As, Bs, acc);

    const int tid = threadIdx.x;
    const int wave = tid >> 6, lane = tid & 63;
    const int quad = lane >> 4, l16 = lane & 15;
    const int wr = (wave >> 1) * 32;
    const int wc = (wave & 1) * 64;
#pragma unroll
    for (int mi = 0; mi < 2; ++mi)
#pragma unroll
        for (int ni = 0; ni < 4; ++ni) {
            int m = m0 + wr + mi * 16 + quad * 4;
            int n = n0 + wc + ni * 16 + l16;
            float b = bo[n];
#pragma unroll
            for (int r = 0; r < 4; ++r) out[(size_t)(m + r) * DM + n] = acc[mi][ni][r] + b;
        }
}

// ---------------- windowed attention: R6 skeleton + DPP max + ones-MFMA sum ------------
// One wave = 16 queries of one head, online softmax over <=10 32-key tiles.
// Changes vs R6 (all targeting the measured serial reduction chain):
//   - row max: 4x ds_bpermute chain -> 4x DPP ops (VALU, no DS pipe)
//   - row sum: 4x ds_bpermute chain -> one MFMA(P, ones) (C-layout broadcasts row sums)
//   - interior tiles (q0-112 <= kt <= q0+97, wave-uniform): skip all mask VALU
__global__ void attn_kernel(const _Float16* __restrict__ Q, const _Float16* __restrict__ K,
                            const _Float16* __restrict__ Vt, _Float16* __restrict__ X) {
    __shared__ _Float16 Pl[4][16][32];
    int tid = threadIdx.x;
    int wave = tid >> 6, lane = tid & 63;
    int quad = lane >> 4, l16 = lane & 15;
    int h = blockIdx.y;
    int bx = ((blockIdx.x & 7) << 3) + (blockIdx.x >> 3);  // XCD-contiguous q-spans
    int q0 = bx * 64 + wave * 16;

    const _Float16* Qp = Q + (size_t)(q0 + l16) * DM + h * DK + quad * 8;
    half8 aq0 = *(const half8*)(Qp);
    half8 aq1 = *(const half8*)(Qp + 32);
    const half8 ones = {(_Float16)1, (_Float16)1, (_Float16)1, (_Float16)1,
                        (_Float16)1, (_Float16)1, (_Float16)1, (_Float16)1};

    float rowM[4], rowL[4];
    f32x4 o[4] = {};
#pragma unroll
    for (int r = 0; r < 4; ++r) { rowM[r] = -__builtin_inff(); rowL[r] = 0.f; }

    int kstart = (q0 > 127) ? ((q0 - 127) & ~31) : 0;
    int kend = q0 + 143;
    if (kend > SEQ - 1) kend = SEQ - 1;

    for (int kt = kstart; kt <= kend; kt += 32) {
        f32x4 s[2];
#pragma unroll
        for (int cf = 0; cf < 2; ++cf) {
            int krow = kt + cf * 16 + l16;  // < SEQ structurally (32-aligned, SEQ%32==0)
            const _Float16* Kp = K + (size_t)krow * DM + h * DK + quad * 8;
            half8 b0 = *(const half8*)(Kp);
            half8 b1 = *(const half8*)(Kp + 32);
            f32x4 z = {};
            z = MFMA16(aq0, b0, z);
            z = MFMA16(aq1, b1, z);
            s[cf] = z;
        }
        // wave-uniform: tile fully inside every row's window?
        const bool full = (kt >= q0 - 112) && (kt <= q0 + 97);
        float alpha[4];
#pragma unroll
        for (int r = 0; r < 4; ++r) {
            float x0 = s[0][r], x1 = s[1][r];
            if (!full) {
                int row = q0 + quad * 4 + r;
                int key0 = kt + l16, key1 = kt + 16 + l16;
                if (key0 < row - 127 || key0 > row + 128) x0 = -1e30f;
                if (key1 < row - 127 || key1 > row + 128) x1 = -1e30f;
            }
            float t = dpp_max16(fmaxf(x0, x1));
            float mnew = fmaxf(rowM[r], t);
            alpha[r] = __expf(rowM[r] - mnew);  // first tile: exp(-inf - finite) = 0
            float p0 = __expf(x0 - mnew);
            float p1 = __expf(x1 - mnew);
            Pl[wave][quad * 4 + r][l16] = (_Float16)p0;
            Pl[wave][quad * 4 + r][l16 + 16] = (_Float16)p1;
            rowM[r] = mnew;
        }
        // P: C-layout -> A-operand layout via per-wave LDS round-trip (wave-internal)
        half8 ap = *(const half8*)&Pl[wave][l16][quad * 8];
        f32x4 ts = {};
        ts = MFMA16(ap, ones, ts);  // ts[r] = this tile's row sum (all cols identical)
#pragma unroll
        for (int r = 0; r < 4; ++r) rowL[r] = rowL[r] * alpha[r] + ts[r];
#pragma unroll
        for (int ni = 0; ni < 4; ++ni) {
#pragma unroll
            for (int r = 0; r < 4; ++r) o[ni][r] *= alpha[r];
            const _Float16* Vp = Vt + (size_t)(h * DK + ni * 16 + l16) * SEQ + kt + quad * 8;
            half8 bv = *(const half8*)(Vp);
            o[ni] = MFMA16(ap, bv, o[ni]);
        }
    }

    float rinv[4];
#pragma unroll
    for (int r = 0; r < 4; ++r) rinv[r] = 1.0f / rowL[r];
#pragma unroll
    for (int ni = 0; ni < 4; ++ni) {
        int n = h * DK + ni * 16 + l16;
#pragma unroll
        for (int r = 0; r < 4; ++r) {
            int m = q0 + quad * 4 + r;
            X[(size_t)m * DM + n] = (_Float16)(o[ni][r] * rinv[r]);
        }
    }
}

extern "C" void kernel_launch(void* const* d_in, const int* in_sizes, int n_in, void* d_out,
                              int out_size, void* d_ws, size_t ws_size, hipStream_t stream) {
    const float* q  = (const float*)d_in[0];
    const float* k  = (const float*)d_in[1];
    const float* v  = (const float*)d_in[2];
    const float* wq = (const float*)d_in[3];
    const float* bq = (const float*)d_in[4];
    const float* wk = (const float*)d_in[5];
    const float* bk = (const float*)d_in[6];
    const float* wv = (const float*)d_in[7];
    const float* bv = (const float*)d_in[8];
    const float* wo = (const float*)d_in[9];
    const float* bo = (const float*)d_in[10];

    const size_t SZ_T = (size_t)SEQ * DM * sizeof(_Float16);  // 8 MB
    const size_t SZ_W = (size_t)DM * DM * sizeof(_Float16);   // 2 MB
    char* p = (char*)d_ws;
    _Float16* qh  = (_Float16*)(p);
    _Float16* kh  = (_Float16*)(p + SZ_T);
    _Float16* vh  = (_Float16*)(p + 2 * SZ_T);
    _Float16* wqh = (_Float16*)(p + 3 * SZ_T);
    _Float16* wkh = (_Float16*)(p + 3 * SZ_T + SZ_W);
    _Float16* wvh = (_Float16*)(p + 3 * SZ_T + 2 * SZ_W);
    _Float16* woh = (_Float16*)(p + 3 * SZ_T + 3 * SZ_W);
    _Float16* Qo  = (_Float16*)(p + 3 * SZ_T + 4 * SZ_W);
    _Float16* Ko  = (_Float16*)(p + 4 * SZ_T + 4 * SZ_W);
    _Float16* Vt  = (_Float16*)(p + 5 * SZ_T + 4 * SZ_W);
    _Float16* Xh  = qh;  // alias: qh dead after gemm_qkv (stream-serialized)

    cvt_all<<<dim3(2048, 7), 256, 0, stream>>>(q, k, v, wq, wk, wv, wo, qh, kh, vh, wqh, wkh,
                                               wvh, woh);
    gemm_qkv<<<dim3(32, 8, 3), 256, 0, stream>>>(qh, kh, vh, wqh, wkh, wvh, bq, bk, bv, Qo, Ko,
                                                 Vt);
    attn_kernel<<<dim3(SEQ / 64, NH), 256, 0, stream>>>(Qo, Ko, Vt, Xh);
    gemm_out<<<dim3(64, 8), 256, 0, stream>>>(Xh, woh, bo, (float*)d_out);
}